// Round 1
// baseline (122.514 us; speedup 1.0000x reference)
//
#include <hip/hip_runtime.h>
#include <hip/hip_bf16.h>

// ---- problem constants -----------------------------------------------------
#define NBATCH 64          // 4*16 collapsed
#define M_DIM  1024
#define K_DIM  256
#define N_DIM  1024

typedef __attribute__((ext_vector_type(8))) short  short8;   // 8 bf16 (4 VGPR)
typedef __attribute__((ext_vector_type(4))) float  f32x4;    // MFMA acc

// quantize to int4 grid, value kept as float (matches reference bit-exactly:
// IEEE fp32 divide + rintf(round-half-even) + clip)
__device__ __forceinline__ float quant4(float v, float clip) {
    float r = rintf(v / clip);
    return fminf(fmaxf(r, -8.0f), 7.0f);
}

// small integers are exact in bf16: low 16 mantissa bits are zero -> truncate
__device__ __forceinline__ unsigned short f2bf(float v) {
    return (unsigned short)(__float_as_uint(v) >> 16);
}

// ---- pass 1a: quantize x -> bf16 int grid, straight copy -------------------
__global__ __launch_bounds__(256) void quant_x_kernel(
        const float* __restrict__ x, const float* __restrict__ clip_p,
        unsigned short* __restrict__ qx) {
    const float clip = clip_p[0];
    const int idx = (blockIdx.x * 256 + threadIdx.x) * 8;
    f32x4 v0 = *(const f32x4*)(x + idx);
    f32x4 v1 = *(const f32x4*)(x + idx + 4);
    short8 o;
    o[0] = (short)f2bf(quant4(v0[0], clip));
    o[1] = (short)f2bf(quant4(v0[1], clip));
    o[2] = (short)f2bf(quant4(v0[2], clip));
    o[3] = (short)f2bf(quant4(v0[3], clip));
    o[4] = (short)f2bf(quant4(v1[0], clip));
    o[5] = (short)f2bf(quant4(v1[1], clip));
    o[6] = (short)f2bf(quant4(v1[2], clip));
    o[7] = (short)f2bf(quant4(v1[3], clip));
    *(short8*)(qx + idx) = o;
}

// ---- pass 1b: quantize + transpose y -> qyT[b][n][k] bf16 ------------------
// block (64,4), grid (N/64, K/64, NBATCH); 64x64 tile via padded LDS
__global__ __launch_bounds__(256) void quant_transpose_y_kernel(
        const float* __restrict__ y, const float* __restrict__ clip_p,
        unsigned short* __restrict__ qyT) {
    __shared__ float tile[64][65];            // +1 pad: conflict-free both phases
    const float clip = clip_p[0];
    const int tx = threadIdx.x;               // 0..63
    const int ty = threadIdx.y;               // 0..3
    const int n0 = blockIdx.x * 64;
    const int k0 = blockIdx.y * 64;
    const int b  = blockIdx.z;
    const float* yb = y + (size_t)b * K_DIM * N_DIM;
#pragma unroll
    for (int i = 0; i < 16; ++i) {
        int kl = ty + i * 4;                  // local k row
        float v = yb[(size_t)(k0 + kl) * N_DIM + n0 + tx];   // coalesced 256B/wave
        tile[kl][tx] = quant4(v, clip);
    }
    __syncthreads();
    unsigned short* ob = qyT + (size_t)b * N_DIM * K_DIM;
#pragma unroll
    for (int i = 0; i < 16; ++i) {
        int nl = ty + i * 4;                  // local n row of output
        ob[(size_t)(n0 + nl) * K_DIM + k0 + tx] = f2bf(tile[tx][nl]); // coalesced
    }
}

// ---- pass 2: batched bf16 MFMA GEMM (m97 structure) ------------------------
// A = qx[b] MxK row-major, BT = qyT[b] NxK row-major, C = out[b] MxN fp32.
// 128x128 tile, BK=32, 4 waves (2x2), 4x4 16x16 fragments per wave.
#define GLD16(gp, lp) __builtin_amdgcn_global_load_lds(                         \
    (const __attribute__((address_space(1))) void*)(gp),                        \
    (__attribute__((address_space(3))) void*)(lp), 16, 0, 0)

__global__ __launch_bounds__(256) void q4_gemm_kernel(
        const unsigned short* __restrict__ qx,
        const unsigned short* __restrict__ qyT,
        const float* __restrict__ xclip_p, const float* __restrict__ yclip_p,
        float* __restrict__ out) {
    // XCD-chunked swizzle: 4096 wgs, 8 XCDs -> logical = (p%8)*512 + p/8
    // puts each batch's 64 blocks on one XCD (per-batch 1MB bf16 fits 4MB L2)
    const int p = blockIdx.x;
    const int l = (p & 7) * 512 + (p >> 3);
    const int b  = l >> 6;                    // batch 0..63
    const int t  = l & 63;
    const int br = t >> 3;                    // tile row 0..7
    const int bc = t & 7;                     // tile col 0..7

    __shared__ __align__(16) unsigned short As[128 * 32];  // [row][k] 64B rows
    __shared__ __align__(16) unsigned short Bs[128 * 32];  // [n-row][k]

    const int tid  = threadIdx.x;
    const int lane = tid & 63;
    const int wid  = tid >> 6;
    const int wr   = wid >> 1;                // wave row 0..1
    const int wc   = wid & 1;                 // wave col 0..1

    const unsigned short* Abase = qx  + (size_t)b * M_DIM * K_DIM + (size_t)br * 128 * K_DIM;
    const unsigned short* Bbase = qyT + (size_t)b * N_DIM * K_DIM + (size_t)bc * 128 * K_DIM;

    f32x4 acc[4][4] = {};

    const int lrow15 = lane & 15;
    const int kchunk = (lane >> 4) * 8;       // 8 consecutive k per lane

    for (int kt = 0; kt < K_DIM / 32; ++kt) { // 8 K-steps
        const int k0 = kt * 32;
        // stage: 8KB A + 8KB B, 16B/lane, 2 chunks each per thread.
        // LDS dest = wave-uniform base + lane*16 (linear, required by HW)
#pragma unroll
        for (int c = 0; c < 2; ++c) {
            int chunk = tid + c * 256;        // 0..511
            int row   = chunk >> 2;           // 0..127
            int kc    = (chunk & 3) * 8;      // 0,8,16,24
            GLD16(Abase + (size_t)row * K_DIM + k0 + kc, As + chunk * 8);
            GLD16(Bbase + (size_t)row * K_DIM + k0 + kc, Bs + chunk * 8);
        }
        __syncthreads();                      // drains vmcnt -> LDS ready

        short8 af[4], bfr[4];
#pragma unroll
        for (int m = 0; m < 4; ++m) {
            int row = wr * 64 + m * 16 + lrow15;
            af[m] = *(const short8*)(As + row * 32 + kchunk);   // ds_read_b128
        }
#pragma unroll
        for (int n = 0; n < 4; ++n) {
            int row = wc * 64 + n * 16 + lrow15;
            bfr[n] = *(const short8*)(Bs + row * 32 + kchunk);
        }
#pragma unroll
        for (int m = 0; m < 4; ++m)
#pragma unroll
            for (int n = 0; n < 4; ++n)
                acc[m][n] = __builtin_amdgcn_mfma_f32_16x16x32_bf16(
                                af[m], bfr[n], acc[m][n], 0, 0, 0);
        __syncthreads();                      // protect LDS before next stage
    }

    // epilogue: C/D layout col=lane&15, row=(lane>>4)*4+j  [verified m89/m91]
    const float scale = xclip_p[0] * yclip_p[0];
    const size_t cb = (size_t)b * M_DIM * N_DIM;
    const int rbase = br * 128 + wr * 64 + (lane >> 4) * 4;
    const int cbase = bc * 128 + wc * 64 + lrow15;
#pragma unroll
    for (int m = 0; m < 4; ++m)
#pragma unroll
        for (int n = 0; n < 4; ++n)
#pragma unroll
            for (int j = 0; j < 4; ++j) {
                int rr = rbase + m * 16 + j;
                int cc = cbase + n * 16;
                out[cb + (size_t)rr * N_DIM + cc] = acc[m][n][j] * scale;
            }
}

// ---- launcher --------------------------------------------------------------
extern "C" void kernel_launch(void* const* d_in, const int* in_sizes, int n_in,
                              void* d_out, int out_size, void* d_ws, size_t ws_size,
                              hipStream_t stream) {
    const float* x     = (const float*)d_in[0];   // [4,16,1024,256]
    const float* y     = (const float*)d_in[1];   // [4,16,256,1024]
    const float* xclip = (const float*)d_in[2];   // scalar
    const float* yclip = (const float*)d_in[3];   // scalar
    float* out = (float*)d_out;                   // [4,16,1024,1024] fp32

    // workspace: qx bf16 32MB + qyT bf16 32MB = 64MB
    unsigned short* qx  = (unsigned short*)d_ws;
    unsigned short* qyT = qx + (size_t)NBATCH * M_DIM * K_DIM;

    // pass 1a: 16777216 elems / (256 thr * 8 elem) = 8192 blocks
    quant_x_kernel<<<8192, 256, 0, stream>>>(x, xclip, qx);
    // pass 1b: 64x64 tiles: (1024/64, 256/64, 64)
    quant_transpose_y_kernel<<<dim3(16, 4, 64), dim3(64, 4), 0, stream>>>(y, yclip, qyT);
    // pass 2: 64 batches x 8x8 tiles = 4096 blocks
    q4_gemm_kernel<<<4096, 256, 0, stream>>>(qx, qyT, xclip, yclip, out);
}

// Round 2
// 104.931 us; speedup vs baseline: 1.1676x; 1.1676x over previous
//
#include <hip/hip_runtime.h>
#include <hip/hip_bf16.h>

// ---- problem constants -----------------------------------------------------
#define NBATCH 64          // 4*16 collapsed
#define M_DIM  1024
#define K_DIM  256
#define N_DIM  1024

typedef __attribute__((ext_vector_type(4)))  int   i32x4;
typedef __attribute__((ext_vector_type(4)))  float f32x4;
typedef __attribute__((ext_vector_type(16))) char  c8x16;

union Pack16 { c8x16 c; i32x4 i; };

// exact reference semantics: IEEE fp32 divide + rintf (round-half-even) + clip
__device__ __forceinline__ int quant4i(float v, float clip) {
    float r = rintf(v / clip);
    r = fminf(fmaxf(r, -8.0f), 7.0f);
    return (int)r;                 // exact: r is an integer in [-8,7]
}

// ---- pass 1a: quantize x -> int8, straight copy ----------------------------
// 16 elems/thread: 64B loads, 16B stores
__global__ __launch_bounds__(256) void quant_x_kernel(
        const float* __restrict__ x, const float* __restrict__ clip_p,
        char* __restrict__ qx) {
    const float clip = clip_p[0];
    const int idx = (blockIdx.x * 256 + threadIdx.x) * 16;
    Pack16 o;
#pragma unroll
    for (int c = 0; c < 4; ++c) {
        f32x4 v = *(const f32x4*)(x + idx + c * 4);
#pragma unroll
        for (int j = 0; j < 4; ++j)
            o.c[c * 4 + j] = (char)quant4i(v[j], clip);
    }
    *(i32x4*)(qx + idx) = o.i;
}

// ---- pass 1b: quantize + transpose y -> qyT[b][n][k] int8 ------------------
// block (64,4), grid (N/64, K/64, NBATCH); 64x64 tile via padded LDS
__global__ __launch_bounds__(256) void quant_transpose_y_kernel(
        const float* __restrict__ y, const float* __restrict__ clip_p,
        char* __restrict__ qyT) {
    __shared__ float tile[64][65];            // quantized values (still exact floats)
    const float clip = clip_p[0];
    const int tx = threadIdx.x;               // 0..63
    const int ty = threadIdx.y;               // 0..3
    const int tid = ty * 64 + tx;
    const int n0 = blockIdx.x * 64;
    const int k0 = blockIdx.y * 64;
    const int b  = blockIdx.z;
    const float* yb = y + (size_t)b * K_DIM * N_DIM;
#pragma unroll
    for (int i = 0; i < 16; ++i) {
        int kl = ty + i * 4;                  // local k row
        float v = yb[(size_t)(k0 + kl) * N_DIM + n0 + tx];   // coalesced
        tile[kl][tx] = fminf(fmaxf(rintf(v / clip), -8.0f), 7.0f);
    }
    __syncthreads();
    // phase 2: each thread emits 16 consecutive k for one n-row -> 16B store
    char* ob = qyT + (size_t)b * N_DIM * K_DIM;
    const int nl = tid >> 2;                  // 0..63 output row (n)
    const int kc = (tid & 3) * 16;            // 0,16,32,48
    Pack16 o;
#pragma unroll
    for (int j = 0; j < 16; ++j)
        o.c[j] = (char)tile[kc + j][nl];      // padded stride -> ~2-way banks
    *(i32x4*)(ob + (size_t)(n0 + nl) * K_DIM + k0 + kc) = o.i;
}

// ---- pass 2: batched i8 MFMA GEMM (m97 structure, BK=64) -------------------
// A = qx[b] MxK row-major i8, BT = qyT[b] NxK row-major i8, C = out[b] MxN f32.
// 128x128 tile, BK=64, 4 waves (2x2), 4x4 16x16 fragments, mfma_i32_16x16x64_i8.
#define GLD16(gp, lp) __builtin_amdgcn_global_load_lds(                         \
    (const __attribute__((address_space(1))) void*)(gp),                        \
    (__attribute__((address_space(3))) void*)(lp), 16, 0, 0)

__global__ __launch_bounds__(256) void q4_gemm_kernel(
        const char* __restrict__ qx,
        const char* __restrict__ qyT,
        const float* __restrict__ xclip_p, const float* __restrict__ yclip_p,
        float* __restrict__ out) {
    // XCD-chunked swizzle: 4096 wgs / 8 XCDs -> 8 consecutive batches per XCD
    const int p = blockIdx.x;
    const int l = (p & 7) * 512 + (p >> 3);
    const int b  = l >> 6;                    // batch 0..63
    const int t  = l & 63;
    const int br = t >> 3;                    // tile row 0..7
    const int bc = t & 7;                     // tile col 0..7

    __shared__ __align__(16) char As[128 * 64];   // [row][k] 64B rows
    __shared__ __align__(16) char Bs[128 * 64];   // [n-row][k]

    const int tid  = threadIdx.x;
    const int lane = tid & 63;
    const int wid  = tid >> 6;
    const int wr   = wid >> 1;                // wave row 0..1
    const int wc   = wid & 1;                 // wave col 0..1

    const char* Abase = qx  + (size_t)b * M_DIM * K_DIM + (size_t)br * 128 * K_DIM;
    const char* Bbase = qyT + (size_t)b * N_DIM * K_DIM + (size_t)bc * 128 * K_DIM;

    i32x4 acc[4][4] = {};

    const int lrow15 = lane & 15;
    const int kchunk = (lane >> 4) * 16;      // 16 consecutive k (bytes) per lane

#pragma unroll
    for (int kt = 0; kt < K_DIM / 64; ++kt) { // 4 K-steps
        const int k0 = kt * 64;
        // stage: 8KB A + 8KB B, 16B/lane; LDS dest = uniform base + lane*16
#pragma unroll
        for (int c = 0; c < 2; ++c) {
            int chunk = tid + c * 256;        // 0..511
            int row   = chunk >> 2;           // 0..127
            int kc    = (chunk & 3) * 16;     // 0,16,32,48
            GLD16(Abase + (size_t)row * K_DIM + k0 + kc, As + chunk * 16);
            GLD16(Bbase + (size_t)row * K_DIM + k0 + kc, Bs + chunk * 16);
        }
        __syncthreads();                      // drains vmcnt -> LDS ready

        i32x4 af[4], bfr[4];
#pragma unroll
        for (int m = 0; m < 4; ++m) {
            int row = wr * 64 + m * 16 + lrow15;
            af[m] = *(const i32x4*)(As + row * 64 + kchunk);   // ds_read_b128
        }
#pragma unroll
        for (int n = 0; n < 4; ++n) {
            int row = wc * 64 + n * 16 + lrow15;
            bfr[n] = *(const i32x4*)(Bs + row * 64 + kchunk);
        }
#pragma unroll
        for (int m = 0; m < 4; ++m)
#pragma unroll
            for (int n = 0; n < 4; ++n)
                acc[m][n] = __builtin_amdgcn_mfma_i32_16x16x64_i8(
                                af[m], bfr[n], acc[m][n], 0, 0, 0);
        __syncthreads();                      // protect LDS before next stage
    }

    // epilogue: C/D layout col=lane&15, row=(lane>>4)*4+j (dtype-independent)
    const float scale = xclip_p[0] * yclip_p[0];
    const size_t cb = (size_t)b * M_DIM * N_DIM;
    const int rbase = br * 128 + wr * 64 + (lane >> 4) * 4;
    const int cbase = bc * 128 + wc * 64 + lrow15;
#pragma unroll
    for (int m = 0; m < 4; ++m)
#pragma unroll
        for (int n = 0; n < 4; ++n)
#pragma unroll
            for (int j = 0; j < 4; ++j) {
                int rr = rbase + m * 16 + j;
                int cc = cbase + n * 16;
                float v = (float)acc[m][n][j] * scale;
                // output written once, never read: keep it out of L2/L3
                __builtin_nontemporal_store(v, &out[cb + (size_t)rr * N_DIM + cc]);
            }
}

// ---- launcher --------------------------------------------------------------
extern "C" void kernel_launch(void* const* d_in, const int* in_sizes, int n_in,
                              void* d_out, int out_size, void* d_ws, size_t ws_size,
                              hipStream_t stream) {
    const float* x     = (const float*)d_in[0];   // [4,16,1024,256]
    const float* y     = (const float*)d_in[1];   // [4,16,256,1024]
    const float* xclip = (const float*)d_in[2];   // scalar
    const float* yclip = (const float*)d_in[3];   // scalar
    float* out = (float*)d_out;                   // [4,16,1024,1024] fp32

    // workspace: qx i8 16MB + qyT i8 16MB = 32MB
    char* qx  = (char*)d_ws;
    char* qyT = qx + (size_t)NBATCH * M_DIM * K_DIM;

    // pass 1a: 16777216 elems / (256 thr * 16 elem) = 4096 blocks
    quant_x_kernel<<<4096, 256, 0, stream>>>(x, xclip, qx);
    // pass 1b: 64x64 tiles: (1024/64, 256/64, 64)
    quant_transpose_y_kernel<<<dim3(16, 4, 64), dim3(64, 4), 0, stream>>>(y, yclip, qyT);
    // pass 2: 64 batches x 8x8 tiles = 4096 blocks
    q4_gemm_kernel<<<4096, 256, 0, stream>>>(qx, qyT, xclip, yclip, out);
}

// Round 3
// 82.940 us; speedup vs baseline: 1.4771x; 1.2651x over previous
//
#include <hip/hip_runtime.h>

// ---- problem constants -----------------------------------------------------
#define NBATCH 64          // 4*16 collapsed
#define M_DIM  1024
#define K_DIM  256
#define N_DIM  1024

typedef __attribute__((ext_vector_type(4)))  int   i32x4;
typedef __attribute__((ext_vector_type(4)))  float f32x4;

union Pack16 { char c[16]; i32x4 i; };

// exact reference semantics: IEEE fp32 divide + rintf (round-half-even) + clip
__device__ __forceinline__ float quant4f(float v, float clip) {
    return fminf(fmaxf(rintf(v / clip), -8.0f), 7.0f);
}

// ---- pass 1: fused quantization --------------------------------------------
// blocks 0..4095   : quantize x -> qx i8 (straight copy, 16 elem/thread)
// blocks 4096..8191: quantize+transpose y -> qyT[b][n][k] i8 (64x64 LDS tiles)
__global__ __launch_bounds__(256) void quant_kernel(
        const float* __restrict__ x, const float* __restrict__ y,
        const float* __restrict__ xclip_p, const float* __restrict__ yclip_p,
        char* __restrict__ qx, char* __restrict__ qyT) {
    __shared__ float tile[64][65];            // +1 pad: <=2-way banks both phases
    const int bid = blockIdx.x;
    const int tid = threadIdx.x;

    if (bid < 4096) {                         // ---- x path ----
        const float clip = xclip_p[0];
        const int idx = (bid * 256 + tid) * 16;
        Pack16 o;
#pragma unroll
        for (int c = 0; c < 4; ++c) {
            f32x4 v = *(const f32x4*)(x + idx + c * 4);
#pragma unroll
            for (int j = 0; j < 4; ++j)
                o.c[c * 4 + j] = (char)(int)quant4f(v[j], clip);
        }
        *(i32x4*)(qx + idx) = o.i;
    } else {                                  // ---- y path ----
        const float clip = yclip_p[0];
        const int b2 = bid - 4096;
        const int n0 = (b2 & 15) * 64;
        const int k0 = ((b2 >> 4) & 3) * 64;
        const int b  = b2 >> 6;
        const float* yb = y + (size_t)b * K_DIM * N_DIM;
        const int kl = tid >> 4;              // 0..15
        const int nq = (tid & 15) * 4;        // 0..60
#pragma unroll
        for (int i = 0; i < 4; ++i) {         // float4 loads, 256B/row-segment
            f32x4 v = *(const f32x4*)(yb + (size_t)(k0 + kl + i * 16) * N_DIM + n0 + nq);
#pragma unroll
            for (int j = 0; j < 4; ++j)
                tile[kl + i * 16][nq + j] = quant4f(v[j], clip);
        }
        __syncthreads();
        // each thread emits 16 consecutive k for one n-row -> 16B store
        char* ob = qyT + (size_t)b * N_DIM * K_DIM;
        const int nl = tid >> 2;              // 0..63
        const int kc = (tid & 3) * 16;        // 0,16,32,48
        Pack16 o;
#pragma unroll
        for (int j = 0; j < 16; ++j)
            o.c[j] = (char)(int)tile[kc + j][nl];
        *(i32x4*)(ob + (size_t)(n0 + nl) * K_DIM + k0 + kc) = o.i;
    }
}

// ---- pass 2: batched i8 MFMA GEMM ------------------------------------------
// A = qx[b] MxK row-major i8, BT = qyT[b] NxK row-major i8, C = out[b] MxN f32.
// 128x128 tile, BK=64, 4 waves (2x2), mfma_i32_16x16x64_i8.
// Staging swizzle (rule #21): linear LDS dest + inverse-swizzled GLOBAL source
// (slot ^= row&3) + swizzled LDS read -> fragment reads 8-way -> 4-way banks.
#define GLD16(gp, lp) __builtin_amdgcn_global_load_lds(                         \
    (const __attribute__((address_space(1))) void*)(gp),                        \
    (__attribute__((address_space(3))) void*)(lp), 16, 0, 0)

__global__ __launch_bounds__(256) void q4_gemm_kernel(
        const char* __restrict__ qx,
        const char* __restrict__ qyT,
        const float* __restrict__ xclip_p, const float* __restrict__ yclip_p,
        float* __restrict__ out) {
    // XCD-chunked swizzle: 4096 wgs / 8 XCDs -> 8 consecutive batches per XCD
    const int p = blockIdx.x;
    const int l = (p & 7) * 512 + (p >> 3);
    const int b  = l >> 6;                    // batch 0..63
    const int t  = l & 63;
    const int br = t >> 3;                    // tile row 0..7
    const int bc = t & 7;                     // tile col 0..7

    // As(8K) + Bs(8K) in main loop; reused as padded C-stage [32][132] (16.9K)
    __shared__ __align__(16) char smem[16896];
    char* As = smem;
    char* Bs = smem + 8192;
    float (*Cst)[132] = (float (*)[132])smem;

    const int tid  = threadIdx.x;
    const int lane = tid & 63;
    const int wid  = tid >> 6;
    const int wr   = wid >> 1;                // wave row 0..1
    const int wc   = wid & 1;                 // wave col 0..1

    const char* Abase = qx  + (size_t)b * M_DIM * K_DIM + (size_t)br * 128 * K_DIM;
    const char* Bbase = qyT + (size_t)b * N_DIM * K_DIM + (size_t)bc * 128 * K_DIM;

    i32x4 acc[4][4] = {};

    const int lrow15 = lane & 15;
    const int s      = lane >> 4;             // k-slot 0..3 (16B each)

#pragma unroll
    for (int kt = 0; kt < K_DIM / 64; ++kt) { // 4 K-steps
        const int k0 = kt * 64;
        // stage 8KB A + 8KB B; LDS dest linear (HW requirement), source swizzled
#pragma unroll
        for (int c = 0; c < 2; ++c) {
            int chunk = tid + c * 256;        // 0..511
            int row   = chunk >> 2;           // 0..127
            int slot  = chunk & 3;
            int ksrc  = ((slot ^ (row & 3)) * 16);
            GLD16(Abase + (size_t)row * K_DIM + k0 + ksrc, As + chunk * 16);
            GLD16(Bbase + (size_t)row * K_DIM + k0 + ksrc, Bs + chunk * 16);
        }
        __syncthreads();                      // drains vmcnt -> LDS ready

        i32x4 af[4], bf[4];
#pragma unroll
        for (int m = 0; m < 4; ++m) {
            int row = wr * 64 + m * 16 + lrow15;
            af[m] = *(const i32x4*)(As + row * 64 + ((s ^ (row & 3)) * 16));
        }
#pragma unroll
        for (int n = 0; n < 4; ++n) {
            int row = wc * 64 + n * 16 + lrow15;
            bf[n] = *(const i32x4*)(Bs + row * 64 + ((s ^ (row & 3)) * 16));
        }
#pragma unroll
        for (int m = 0; m < 4; ++m)
#pragma unroll
            for (int n = 0; n < 4; ++n)
                acc[m][n] = __builtin_amdgcn_mfma_i32_16x16x64_i8(
                                af[m], bf[n], acc[m][n], 0, 0, 0);
        __syncthreads();                      // protect LDS before next stage
    }

    // ---- epilogue: LDS-bounce -> full-line float4 nt stores ----
    // C/D layout col=lane&15, row=(lane>>4)*4+j (dtype-independent)
    const float scale = xclip_p[0] * yclip_p[0];
    const size_t cb = (size_t)b * M_DIM * N_DIM
                    + (size_t)(br * 128) * N_DIM + bc * 128;
    const int rsub = (lane >> 4) * 4;
    const int rdr  = tid >> 3;                // 0..31 read row
    const int cdw0 = (tid & 7) * 4;           // 0..28 col dword base

#pragma unroll
    for (int m = 0; m < 4; ++m) {
        // write 32x128 quadrant (rows wr*16+0..15 per wave) into padded LDS
#pragma unroll
        for (int n = 0; n < 4; ++n)
#pragma unroll
            for (int j = 0; j < 4; ++j)
                Cst[wr * 16 + rsub + j][wc * 64 + n * 16 + lrow15] =
                    (float)acc[m][n][j] * scale;
        __syncthreads();
        // read row-major, store float4: 8 lanes = 128B contiguous line
        const int grow = (rdr >> 4) * 64 + m * 16 + (rdr & 15);
#pragma unroll
        for (int i = 0; i < 4; ++i) {
            f32x4 v = *(const f32x4*)&Cst[rdr][cdw0 + i * 32];
            __builtin_nontemporal_store(
                v, (f32x4*)(out + cb + (size_t)grow * N_DIM + cdw0 + i * 32));
        }
        __syncthreads();                      // before next quadrant overwrite
    }
}

// ---- launcher --------------------------------------------------------------
extern "C" void kernel_launch(void* const* d_in, const int* in_sizes, int n_in,
                              void* d_out, int out_size, void* d_ws, size_t ws_size,
                              hipStream_t stream) {
    const float* x     = (const float*)d_in[0];   // [4,16,1024,256]
    const float* y     = (const float*)d_in[1];   // [4,16,256,1024]
    const float* xclip = (const float*)d_in[2];   // scalar
    const float* yclip = (const float*)d_in[3];   // scalar
    float* out = (float*)d_out;                   // [4,16,1024,1024] fp32

    // workspace: qx i8 16MB + qyT i8 16MB = 32MB
    char* qx  = (char*)d_ws;
    char* qyT = qx + (size_t)NBATCH * M_DIM * K_DIM;

    // fused quant: 4096 x-blocks + 4096 y-tile blocks
    quant_kernel<<<8192, 256, 0, stream>>>(x, y, xclip, yclip, qx, qyT);
    // GEMM: 64 batches x 8x8 tiles = 4096 blocks
    q4_gemm_kernel<<<4096, 256, 0, stream>>>(qx, qyT, xclip, yclip, out);
}

// Round 4
// 80.223 us; speedup vs baseline: 1.5272x; 1.0339x over previous
//
#include <hip/hip_runtime.h>

// ---- problem constants -----------------------------------------------------
#define NBATCH 64          // 4*16 collapsed
#define M_DIM  1024
#define K_DIM  256
#define N_DIM  1024

typedef __attribute__((ext_vector_type(4)))  int   i32x4;
typedef __attribute__((ext_vector_type(4)))  float f32x4;

union Pack16 { char c[16]; i32x4 i; };

// exact reference semantics: IEEE fp32 divide + rintf (round-half-even) + clip
__device__ __forceinline__ float quant4f(float v, float clip) {
    return fminf(fmaxf(rintf(v / clip), -8.0f), 7.0f);
}

// ---- pass 1: fused quantization --------------------------------------------
// blocks 0..4095   : quantize x -> qx i8 (straight copy, 16 elem/thread)
// blocks 4096..8191: quantize+transpose y -> qyT[b][n][k] i8 (64x64 LDS tiles)
__global__ __launch_bounds__(256) void quant_kernel(
        const float* __restrict__ x, const float* __restrict__ y,
        const float* __restrict__ xclip_p, const float* __restrict__ yclip_p,
        char* __restrict__ qx, char* __restrict__ qyT) {
    __shared__ float tile[64][65];            // +1 pad: <=2-way banks both phases
    const int bid = blockIdx.x;
    const int tid = threadIdx.x;

    if (bid < 4096) {                         // ---- x path ----
        const float clip = xclip_p[0];
        const int idx = (bid * 256 + tid) * 16;
        Pack16 o;
#pragma unroll
        for (int c = 0; c < 4; ++c) {
            f32x4 v = *(const f32x4*)(x + idx + c * 4);
#pragma unroll
            for (int j = 0; j < 4; ++j)
                o.c[c * 4 + j] = (char)(int)quant4f(v[j], clip);
        }
        *(i32x4*)(qx + idx) = o.i;
    } else {                                  // ---- y path ----
        const float clip = yclip_p[0];
        const int b2 = bid - 4096;
        const int n0 = (b2 & 15) * 64;
        const int k0 = ((b2 >> 4) & 3) * 64;
        const int b  = b2 >> 6;
        const float* yb = y + (size_t)b * K_DIM * N_DIM;
        const int kl = tid >> 4;              // 0..15
        const int nq = (tid & 15) * 4;        // 0..60
#pragma unroll
        for (int i = 0; i < 4; ++i) {         // float4 loads, 256B/row-segment
            f32x4 v = *(const f32x4*)(yb + (size_t)(k0 + kl + i * 16) * N_DIM + n0 + nq);
#pragma unroll
            for (int j = 0; j < 4; ++j)
                tile[kl + i * 16][nq + j] = quant4f(v[j], clip);
        }
        __syncthreads();
        // each thread emits 16 consecutive k for one n-row -> 16B store
        char* ob = qyT + (size_t)b * N_DIM * K_DIM;
        const int nl = tid >> 2;              // 0..63
        const int kc = (tid & 3) * 16;        // 0,16,32,48
        Pack16 o;
#pragma unroll
        for (int j = 0; j < 16; ++j)
            o.c[j] = (char)(int)tile[kc + j][nl];
        *(i32x4*)(ob + (size_t)(n0 + nl) * K_DIM + k0 + kc) = o.i;
    }
}

// ---- pass 2: batched i8 MFMA GEMM, double-buffered K-loop ------------------
// A = qx[b] MxK row-major i8, BT = qyT[b] NxK row-major i8, C = out[b] MxN f32.
// 128x128 tile, BK=64, 4 waves (2x2), mfma_i32_16x16x64_i8.
// Staging swizzle (rule #21): linear LDS dest + inverse-swizzled GLOBAL source
// (slot ^= row&3) + swizzled LDS read -> fragment reads 16-way -> 4-way banks.
#define GLD16(gp, lp) __builtin_amdgcn_global_load_lds(                         \
    (const __attribute__((address_space(1))) void*)(gp),                        \
    (__attribute__((address_space(3))) void*)(lp), 16, 0, 0)

__global__ __launch_bounds__(256, 4) void q4_gemm_kernel(
        const char* __restrict__ qx,
        const char* __restrict__ qyT,
        const float* __restrict__ xclip_p, const float* __restrict__ yclip_p,
        float* __restrict__ out) {
    // XCD-chunked swizzle: 4096 wgs / 8 XCDs -> 8 consecutive batches per XCD
    const int p = blockIdx.x;
    const int l = (p & 7) * 512 + (p >> 3);
    const int b  = l >> 6;                    // batch 0..63
    const int t  = l & 63;
    const int br = t >> 3;                    // tile row 0..7
    const int bc = t & 7;                     // tile col 0..7

    // double-buffered staging: buf k: A at smem+k*16384, B at +8192 (32KB)
    // epilogue overlays smem as padded C-stage [32][132] f32 (16.9KB)
    __shared__ __align__(16) char smem[32768];
    float (*Cst)[132] = (float (*)[132])smem;

    const int tid  = threadIdx.x;
    const int lane = tid & 63;
    const int wid  = tid >> 6;
    const int wr   = wid >> 1;                // wave row 0..1
    const int wc   = wid & 1;                 // wave col 0..1

    const char* Abase = qx  + (size_t)b * M_DIM * K_DIM + (size_t)br * 128 * K_DIM;
    const char* Bbase = qyT + (size_t)b * N_DIM * K_DIM + (size_t)bc * 128 * K_DIM;

    // per-thread staging coordinates (2 chunks of 16B for A, 2 for B)
    const int row0  = tid >> 2;               // chunks 0..255  -> rows 0..63
    const int row1  = (tid + 256) >> 2;       // chunks 256..511-> rows 64..127
    const int slot  = tid & 3;
    const int ks0   = (slot ^ (row0 & 3)) * 16;
    const int ks1   = (slot ^ (row1 & 3)) * 16;

    i32x4 acc[4][4] = {};

    const int lrow15 = lane & 15;
    const int s      = lane >> 4;             // k-slot 0..3 (16B each)

    // ---- prologue: stage K-step 0 into buf 0 ----
    {
        char* As = smem; char* Bs = smem + 8192;
        GLD16(Abase + (size_t)row0 * K_DIM + ks0, As + tid * 16);
        GLD16(Bbase + (size_t)row0 * K_DIM + ks0, Bs + tid * 16);
        GLD16(Abase + (size_t)row1 * K_DIM + ks1, As + (tid + 256) * 16);
        GLD16(Bbase + (size_t)row1 * K_DIM + ks1, Bs + (tid + 256) * 16);
    }
    __syncthreads();                          // vmcnt(0) drain + barrier

#pragma unroll
    for (int kt = 0; kt < 4; ++kt) {          // 4 K-steps of 64
        char* As = smem + (kt & 1) * 16384;
        char* Bs = As + 8192;
        // issue next K-step's loads into the other buffer (overlaps compute)
        if (kt < 3) {
            const int kn = (kt + 1) * 64;
            char* An = smem + ((kt + 1) & 1) * 16384;
            char* Bn = An + 8192;
            GLD16(Abase + (size_t)row0 * K_DIM + kn + ks0, An + tid * 16);
            GLD16(Bbase + (size_t)row0 * K_DIM + kn + ks0, Bn + tid * 16);
            GLD16(Abase + (size_t)row1 * K_DIM + kn + ks1, An + (tid + 256) * 16);
            GLD16(Bbase + (size_t)row1 * K_DIM + kn + ks1, Bn + (tid + 256) * 16);
        }

        i32x4 af[4], bf[4];
#pragma unroll
        for (int m = 0; m < 4; ++m) {
            int row = wr * 64 + m * 16 + lrow15;
            af[m] = *(const i32x4*)(As + row * 64 + ((s ^ (row & 3)) * 16));
        }
#pragma unroll
        for (int n = 0; n < 4; ++n) {
            int row = wc * 64 + n * 16 + lrow15;
            bf[n] = *(const i32x4*)(Bs + row * 64 + ((s ^ (row & 3)) * 16));
        }
#pragma unroll
        for (int m = 0; m < 4; ++m)
#pragma unroll
            for (int n = 0; n < 4; ++n)
                acc[m][n] = __builtin_amdgcn_mfma_i32_16x16x64_i8(
                                af[m], bf[n], acc[m][n], 0, 0, 0);
        // one barrier per step: drains this wave's vmcnt (next buf ready) and
        // guarantees all waves finished reading the current buf before reuse
        __syncthreads();
    }

    // ---- epilogue: LDS-bounce -> full-line float4 nt stores ----
    // C/D layout col=lane&15, row=(lane>>4)*4+j (dtype-independent)
    const float scale = xclip_p[0] * yclip_p[0];
    const size_t cb = (size_t)b * M_DIM * N_DIM
                    + (size_t)(br * 128) * N_DIM + bc * 128;
    const int rsub = (lane >> 4) * 4;
    const int rdr  = tid >> 3;                // 0..31 read row
    const int cdw0 = (tid & 7) * 4;           // 0..28 col dword base

#pragma unroll
    for (int m = 0; m < 4; ++m) {
        // write 32x128 quadrant (rows wr*16+0..15 per wave) into padded LDS
#pragma unroll
        for (int n = 0; n < 4; ++n)
#pragma unroll
            for (int j = 0; j < 4; ++j)
                Cst[wr * 16 + rsub + j][wc * 64 + n * 16 + lrow15] =
                    (float)acc[m][n][j] * scale;
        __syncthreads();
        // read row-major, store float4: 8 lanes = 128B contiguous line
        const int grow = (rdr >> 4) * 64 + m * 16 + (rdr & 15);
#pragma unroll
        for (int i = 0; i < 4; ++i) {
            f32x4 v = *(const f32x4*)&Cst[rdr][cdw0 + i * 32];
            __builtin_nontemporal_store(
                v, (f32x4*)(out + cb + (size_t)grow * N_DIM + cdw0 + i * 32));
        }
        __syncthreads();                      // before next quadrant overwrite
    }
}

// ---- launcher --------------------------------------------------------------
extern "C" void kernel_launch(void* const* d_in, const int* in_sizes, int n_in,
                              void* d_out, int out_size, void* d_ws, size_t ws_size,
                              hipStream_t stream) {
    const float* x     = (const float*)d_in[0];   // [4,16,1024,256]
    const float* y     = (const float*)d_in[1];   // [4,16,256,1024]
    const float* xclip = (const float*)d_in[2];   // scalar
    const float* yclip = (const float*)d_in[3];   // scalar
    float* out = (float*)d_out;                   // [4,16,1024,1024] fp32

    // workspace: qx i8 16MB + qyT i8 16MB = 32MB
    char* qx  = (char*)d_ws;
    char* qyT = qx + (size_t)NBATCH * M_DIM * K_DIM;

    // fused quant: 4096 x-blocks + 4096 y-tile blocks
    quant_kernel<<<8192, 256, 0, stream>>>(x, y, xclip, yclip, qx, qyT);
    // GEMM: 64 batches x 8x8 tiles = 4096 blocks
    q4_gemm_kernel<<<4096, 256, 0, stream>>>(qx, qyT, xclip, yclip, out);
}